// Round 4
// baseline (245.238 us; speedup 1.0000x reference)
//
#include <hip/hip_runtime.h>
#include <hip/hip_bf16.h>
#include <math.h>

// Problem constants (fixed by setup_inputs)
#define N_NODES 1024
#define F_DIM   1024
#define H_DIM   512
#define E_EDGES 32768
#define B_GRAPHS 16
#define OUT_DIM 10
#define FH_DIM  1536
#define EPS 1e-5f
#define MH_C_F 0.8673250705840776f
#define INV_SQRT2 0.70710678118654752440f

typedef float v2f __attribute__((ext_vector_type(2)));

#if __has_builtin(__builtin_amdgcn_exp2f)
#define EXP2F(x) __builtin_amdgcn_exp2f(x)
#define CEXP (-0.72134752044448170368f)   // -0.5 * log2(e)
#else
#define EXP2F(x) __expf(x)
#define CEXP (-0.5f)
#endif

// ---------------- K_pre: fused h / param-pack / x-stats / deg-zero ----------------
// blocks [0,2048): h;  [2048,3072): pk;  [3072,3088): x col-stat partials; [3088,3092): deg=0
__global__ __launch_bounds__(256) void k_pre(const float* __restrict__ x,
                                             const float* __restrict__ watt,
                                             const float* __restrict__ scale,
                                             const float* __restrict__ trans,
                                             const float* __restrict__ ww,
                                             const float* __restrict__ bw,
                                             float* __restrict__ h,
                                             float* __restrict__ pk,
                                             float* __restrict__ xpart,
                                             float* __restrict__ xpart2,
                                             int* __restrict__ deg) {
    const int b = blockIdx.x;
    const int t = threadIdx.x;
    if (b < 2048) {
        int idx = b * 256 + t;                 // 0 .. N*H-1
        float2 p = ((const float2*)x)[idx];
        float lo = (p.x + p.y) * INV_SQRT2;
        float hi = (p.x - p.y) * INV_SQRT2;
        float tt = lo * watt[0] + hi * watt[1];
        float sc = 1.0f / (1.0f + __expf(-tt));
        h[idx] = sc * lo + (1.0f - sc) * hi;
    } else if (b < 3072) {
        int g = (b - 2048) * 256 + t;          // 0 .. H*H-1
        float iv = 1.0f / scale[g];
        float4 p;
        p.x = iv;
        p.y = trans[g] * iv;
        p.z = ww[g];
        p.w = bw[g];
        ((float4*)pk)[g] = p;
    } else if (b < 3088) {
        int gr = b - 3072;                     // row group, 64 rows
        float s[4] = {}, s2[4] = {};
        for (int r = 0; r < 64; ++r) {
            int row = gr * 64 + r;
            #pragma unroll
            for (int ch = 0; ch < 4; ++ch) {
                float v = x[row * F_DIM + ch * 256 + t];
                s[ch] += v; s2[ch] += v * v;
            }
        }
        #pragma unroll
        for (int ch = 0; ch < 4; ++ch) {
            xpart [gr * F_DIM + ch * 256 + t] = s[ch];
            xpart2[gr * F_DIM + ch * 256 + t] = s2[ch];
        }
    } else {
        int i = (b - 3088) * 256 + t;
        deg[i] = 0;
    }
}

// ---------------- edge bucketing (counting sort by dst) ----------------
__global__ __launch_bounds__(256) void k_hist(const int* __restrict__ dst,
                                              int* __restrict__ deg) {
    int e = blockIdx.x * 256 + threadIdx.x;
    atomicAdd(&deg[dst[e]], 1);
}

// block 0: exclusive scan of deg; block 1: graph ranges from sorted batch
__global__ __launch_bounds__(1024) void k_scan2(const int* __restrict__ deg,
                                                int* __restrict__ start,
                                                int* __restrict__ cursor,
                                                const int* __restrict__ batch,
                                                int* __restrict__ gstart,
                                                int* __restrict__ gcnt) {
    int t = threadIdx.x;
    if (blockIdx.x == 0) {
        __shared__ int sh[N_NODES];
        int d0 = deg[t];
        sh[t] = d0;
        __syncthreads();
        for (int off = 1; off < N_NODES; off <<= 1) {
            int v = (t >= off) ? sh[t - off] : 0;
            __syncthreads();
            sh[t] += v;
            __syncthreads();
        }
        int excl = sh[t] - d0;
        start[t] = excl;
        cursor[t] = excl;
    } else {
        __shared__ int cnt_sh[B_GRAPHS];
        __shared__ int start_sh[B_GRAPHS];
        if (t < B_GRAPHS) { cnt_sh[t] = 0; start_sh[t] = 0; }
        __syncthreads();
        int bb = batch[t];
        atomicAdd(&cnt_sh[bb], 1);
        if (t == 0 || batch[t - 1] != bb) start_sh[bb] = t;
        __syncthreads();
        if (t < B_GRAPHS) { gstart[t] = start_sh[t]; gcnt[t] = cnt_sh[t]; }
    }
}

__global__ __launch_bounds__(256) void k_fill(const int* __restrict__ src,
                                              const int* __restrict__ dst,
                                              int* __restrict__ cursor,
                                              int* __restrict__ elist) {
    int e = blockIdx.x * 256 + threadIdx.x;
    int slot = atomicAdd(&cursor[dst[e]], 1);
    elist[slot] = src[e];
}

// ---------------- K2: gather (atomic-free scatter-add) ----------------
__global__ __launch_bounds__(256) void k_gather(const float* __restrict__ h,
                                                const int* __restrict__ start,
                                                const int* __restrict__ deg,
                                                const int* __restrict__ elist,
                                                float* __restrict__ agg) {
    int d = blockIdx.x;
    int t = threadIdx.x;
    int st = start[d], dg = deg[d];
    float a0 = h[d * H_DIM + t];
    float a1 = h[d * H_DIM + t + 256];
    for (int k = 0; k < dg; ++k) {
        int s = elist[st + k];
        a0 += h[s * H_DIM + t];
        a1 += h[s * H_DIM + t + 256];
    }
    agg[d * H_DIM + t]       = a0;
    agg[d * H_DIM + t + 256] = a1;
}

// ---------------- K2b: transpose agg [n][i] -> aggT [i][n], + siluT ----------------
__global__ __launch_bounds__(256) void k_transpose(const float* __restrict__ agg,
                                                   float* __restrict__ aggT,
                                                   float* __restrict__ siluT) {
    __shared__ float tile[64 * 65];
    const int t = threadIdx.x;
    const int n0 = blockIdx.x * 64;
    const int i0 = blockIdx.y * 64;
    #pragma unroll
    for (int v = 0; v < 4; ++v) {
        int flat = v * 256 + t;
        int r = flat >> 4, c4 = flat & 15;
        float4 a = *(const float4*)&agg[(n0 + r) * H_DIM + i0 + c4 * 4];
        tile[(c4 * 4 + 0) * 65 + r] = a.x;
        tile[(c4 * 4 + 1) * 65 + r] = a.y;
        tile[(c4 * 4 + 2) * 65 + r] = a.z;
        tile[(c4 * 4 + 3) * 65 + r] = a.w;
    }
    __syncthreads();
    #pragma unroll
    for (int v = 0; v < 4; ++v) {
        int flat = v * 256 + t;
        int il = flat >> 4, c4 = flat & 15;
        float4 a;
        a.x = tile[il * 65 + c4 * 4 + 0];
        a.y = tile[il * 65 + c4 * 4 + 1];
        a.z = tile[il * 65 + c4 * 4 + 2];
        a.w = tile[il * 65 + c4 * 4 + 3];
        int g = (i0 + il) * N_NODES + n0 + c4 * 4;
        *(float4*)&aggT[g] = a;
        float4 s;
        s.x = a.x / (1.0f + __expf(-a.x));
        s.y = a.y / (1.0f + __expf(-a.y));
        s.z = a.z / (1.0f + __expf(-a.z));
        s.w = a.w / (1.0f + __expf(-a.w));
        *(float4*)&siluT[g] = s;
    }
}

// ---------------- K3: fused wavelet + base, 4n x 4o per thread, conflict-free LDS ----------------
#define TN 64
#define TO 64
#define KI 8
#define ZSPLIT 8
#define ZLEN (H_DIM / ZSPLIT)   // 64
__global__ __launch_bounds__(256, 4) void k_wavelet(const float* __restrict__ aggT,
                                                    const float* __restrict__ siluT,
                                                    const float* __restrict__ pk,
                                                    float* __restrict__ vbp) {
    __shared__ float sA[KI * TN];        // [ii][n4] float4-packed: f4idx = ii*16 + n4
    __shared__ float sS[KI * TN];
    __shared__ float sP[KI * TO * 4];    // [ii][o] float4: f4idx = ii*64 + o

    const int t  = threadIdx.x;
    const int n0 = blockIdx.x * TN;
    const int o0 = blockIdx.y * TO;
    const int z0 = blockIdx.z * ZLEN;
    const int nl = (t & 15) * 4;         // 4 consecutive n
    const int og = t >> 4;               // o = o0 + og + 16*j

    v2f accw[4][2] = {};   // [j][npair]
    v2f accb[4][2] = {};
    const v2f cexp2 = {CEXP, CEXP};
    const v2f one2  = {1.0f, 1.0f};

    const float4* pk4 = (const float4*)pk;
    float4* sA4 = (float4*)sA;
    float4* sS4 = (float4*)sS;
    float4* sP4 = (float4*)sP;

    for (int stg = 0; stg < ZLEN / KI; ++stg) {
        const int i0 = z0 + stg * KI;
        __syncthreads();
        // stage A/S: 8 i-rows x 16 n-float4s = 128 f4 each; threads<128 -> A, >=128 -> S
        {
            int u = t & 127;
            int ii = u >> 4, n4 = u & 15;
            int g = (i0 + ii) * N_NODES + n0 + n4 * 4;
            if (t < 128) sA4[u] = *(const float4*)&aggT[g];
            else         sS4[u] = *(const float4*)&siluT[g];
        }
        // stage params: 8 i x 64 o float4s = 512 f4, 2 per thread
        #pragma unroll
        for (int j = 0; j < 2; ++j) {
            int u = j * 256 + t;
            int ii = u & 7, o = u >> 3;
            sP4[ii * TO + o] = pk4[(o0 + o) * H_DIM + i0 + ii];
        }
        __syncthreads();
        #pragma unroll
        for (int ii = 0; ii < KI; ++ii) {
            float4 af = sA4[ii * 16 + (t & 15)];
            float4 sf = sS4[ii * 16 + (t & 15)];
            v2f a01 = {af.x, af.y}, a23 = {af.z, af.w};
            v2f s01 = {sf.x, sf.y}, s23 = {sf.z, sf.w};
            #pragma unroll
            for (int j = 0; j < 4; ++j) {
                float4 p = sP4[ii * TO + og + 16 * j];
                v2f iv2 = {p.x, p.x};
                v2f tf2 = {p.y, p.y};
                v2f w2  = {p.z, p.z};
                v2f b2  = {p.w, p.w};
                {
                    v2f xs = a01 * iv2 - tf2;
                    v2f x2 = xs * xs;
                    v2f arg = x2 * cexp2;
                    v2f e; e.x = EXP2F(arg.x); e.y = EXP2F(arg.y);
                    v2f f = e * w2;
                    v2f u2 = one2 - x2;
                    accw[j][0] += u2 * f;
                    accb[j][0] += s01 * b2;
                }
                {
                    v2f xs = a23 * iv2 - tf2;
                    v2f x2 = xs * xs;
                    v2f arg = x2 * cexp2;
                    v2f e; e.x = EXP2F(arg.x); e.y = EXP2F(arg.y);
                    v2f f = e * w2;
                    v2f u2 = one2 - x2;
                    accw[j][1] += u2 * f;
                    accb[j][1] += s23 * b2;
                }
            }
        }
    }
    float* out = vbp + (size_t)blockIdx.z * (N_NODES * H_DIM);
    #pragma unroll
    for (int j = 0; j < 4; ++j) {
        int oc = o0 + og + 16 * j;
        #pragma unroll
        for (int np = 0; np < 2; ++np) {
            int n = n0 + nl + 2 * np;
            out[(n + 0) * H_DIM + oc] = MH_C_F * accw[j][np].x + accb[j][np].x;
            out[(n + 1) * H_DIM + oc] = MH_C_F * accw[j][np].y + accb[j][np].y;
        }
    }
}

// ---------------- K4: reduce partials -> vb + per-strip column stats ----------------
__global__ __launch_bounds__(256) void k_reduce(const float* __restrict__ vbp,
                                                float* __restrict__ vb,
                                                float* __restrict__ vpart,
                                                float* __restrict__ vpart2) {
    const int b = blockIdx.x;           // 64 blocks: 8 o-strips x 8 n-strips
    const int o0 = (b & 7) * 64;
    const int nstrip = b >> 3;
    const int n0 = nstrip * 128;
    const int t = threadIdx.x;
    const int oc = o0 + (t & 63);
    const int nsub = t >> 6;
    float s = 0.f, s2 = 0.f;
    for (int r = 0; r < 32; ++r) {
        int n = n0 + r * 4 + nsub;
        size_t idx = (size_t)n * H_DIM + oc;
        float v = 0.f;
        #pragma unroll
        for (int z = 0; z < ZSPLIT; ++z) v += vbp[z * (N_NODES * H_DIM) + idx];
        vb[idx] = v;
        s += v; s2 += v * v;
    }
    __shared__ float sh1[256], sh2[256];
    sh1[t] = s; sh2[t] = s2;
    __syncthreads();
    if (t < 64) {
        s  = sh1[t] + sh1[t + 64] + sh1[t + 128] + sh1[t + 192];
        s2 = sh2[t] + sh2[t + 64] + sh2[t + 128] + sh2[t + 192];
        vpart [nstrip * H_DIM + o0 + t] = s;
        vpart2[nstrip * H_DIM + o0 + t] = s2;
    }
}

// ---------------- K5: finalize BN affine params ----------------
__global__ __launch_bounds__(256) void k_finalize(const float* __restrict__ vpart,
                                                  const float* __restrict__ vpart2,
                                                  const float* __restrict__ xpart,
                                                  const float* __restrict__ xpart2,
                                                  float* __restrict__ muv,
                                                  float* __restrict__ Sv,
                                                  float* __restrict__ mux,
                                                  float* __restrict__ Sx) {
    int t = threadIdx.x;
    for (int c = t; c < H_DIM; c += 256) {
        float s = 0.f, s2 = 0.f;
        #pragma unroll
        for (int g = 0; g < 8; ++g) { s += vpart[g * H_DIM + c]; s2 += vpart2[g * H_DIM + c]; }
        float mu  = s * (1.0f / N_NODES);
        float var = s2 * (1.0f / N_NODES) - mu * mu;
        if (var < 0.f) var = 0.f;
        float s1v = 1.0f / sqrtf(var + EPS);
        float v1  = var * s1v * s1v;
        float s2v = 1.0f / sqrtf(v1 + EPS);
        float v2  = v1 * s2v * s2v;
        float s3v = 1.0f / sqrtf(v2 + EPS);
        muv[c] = mu;
        Sv[c]  = s1v * s2v * s3v;
    }
    for (int c = t; c < F_DIM; c += 256) {
        float s = 0.f, s2 = 0.f;
        #pragma unroll
        for (int g = 0; g < 16; ++g) { s += xpart[g * F_DIM + c]; s2 += xpart2[g * F_DIM + c]; }
        float mu  = s * (1.0f / N_NODES);
        float var = s2 * (1.0f / N_NODES) - mu * mu;
        if (var < 0.f) var = 0.f;
        mux[c] = mu;
        Sx[c]  = 1.0f / sqrtf(var + EPS);
    }
}

// ---------------- K6: pooled[b,c] = (mean_b(col) - mu)*S, grid (6, B) ----------------
__global__ __launch_bounds__(256) void k_pool(const float* __restrict__ x,
                                              const float* __restrict__ vb,
                                              const int* __restrict__ gstart,
                                              const int* __restrict__ gcnt,
                                              const float* __restrict__ mux,
                                              const float* __restrict__ Sx,
                                              const float* __restrict__ muv,
                                              const float* __restrict__ Sv,
                                              float* __restrict__ pooled) {
    const int b = blockIdx.y;
    const int ch = blockIdx.x;          // 0..5
    const int t = threadIdx.x;
    const int cnt = gcnt[b], st = gstart[b];
    float acc = 0.f;
    if (ch < 4) {
        int c = ch * 256 + t;
        for (int r = 0; r < cnt; ++r) acc += x[(st + r) * F_DIM + c];
        float ic = (cnt > 0) ? 1.0f / (float)cnt : 0.f;
        pooled[b * FH_DIM + c] = (acc * ic - mux[c]) * Sx[c];
    } else {
        int c = (ch - 4) * 256 + t;
        for (int r = 0; r < cnt; ++r) acc += vb[(st + r) * H_DIM + c];
        float ic = (cnt > 0) ? 1.0f / (float)cnt : 0.f;
        pooled[b * FH_DIM + F_DIM + c] = (acc * ic - muv[c]) * Sv[c];
    }
}

// ---------------- K7: fc1 — one wave per o, 16 graph accumulators ----------------
__global__ __launch_bounds__(256) void k_fc1(const float* __restrict__ pooled,
                                             const float* __restrict__ w,
                                             const float* __restrict__ bias,
                                             float* __restrict__ h1) {
    int o = blockIdx.x * 4 + (threadIdx.x >> 6);   // 0..511
    int lane = threadIdx.x & 63;
    float acc[B_GRAPHS] = {};
    const float* wr = w + o * FH_DIM;
    for (int k = lane; k < FH_DIM; k += 64) {
        float wv = wr[k];
        #pragma unroll
        for (int b = 0; b < B_GRAPHS; ++b) acc[b] += wv * pooled[b * FH_DIM + k];
    }
    #pragma unroll
    for (int b = 0; b < B_GRAPHS; ++b) {
        #pragma unroll
        for (int off = 32; off > 0; off >>= 1) acc[b] += __shfl_down(acc[b], off);
    }
    if (lane == 0) {
        float bs = bias[o];
        #pragma unroll
        for (int b = 0; b < B_GRAPHS; ++b)
            h1[b * H_DIM + o] = fmaxf(acc[b] + bs, 0.f);
    }
}

// ---------------- K8: out = h1 @ fc2_w^T + b2 ----------------
__global__ __launch_bounds__(256) void k_fc2(const float* __restrict__ h1,
                                             const float* __restrict__ w,
                                             const float* __restrict__ bias,
                                             float* __restrict__ outp) {
    int wid = (blockIdx.x * 256 + threadIdx.x) >> 6;
    int lane = threadIdx.x & 63;
    if (wid >= B_GRAPHS * OUT_DIM) return;
    int b = wid / OUT_DIM, u = wid % OUT_DIM;
    const float* hr = h1 + b * H_DIM;
    const float* wr = w + u * H_DIM;
    float acc = 0.f;
    for (int k = lane; k < H_DIM; k += 64) acc += hr[k] * wr[k];
    #pragma unroll
    for (int off = 32; off > 0; off >>= 1) acc += __shfl_down(acc, off);
    if (lane == 0) outp[b * OUT_DIM + u] = acc + bias[u];
}

extern "C" void kernel_launch(void* const* d_in, const int* in_sizes, int n_in,
                              void* d_out, int out_size, void* d_ws, size_t ws_size,
                              hipStream_t stream) {
    const float* x       = (const float*)d_in[0];
    const float* w_att   = (const float*)d_in[1];
    const float* wk_scale= (const float*)d_in[2];
    const float* wk_trans= (const float*)d_in[3];
    const float* wk_wav  = (const float*)d_in[4];
    const float* wk_base = (const float*)d_in[5];
    const float* fc1_w   = (const float*)d_in[6];
    const float* fc1_b   = (const float*)d_in[7];
    const float* fc2_w   = (const float*)d_in[8];
    const float* fc2_b   = (const float*)d_in[9];
    const int*   eidx    = (const int*)d_in[10];
    const int*   batch   = (const int*)d_in[11];
    float* outp = (float*)d_out;

    float* ws = (float*)d_ws;
    const int NH = N_NODES * H_DIM;            // 524288
    float* h      = ws;                        // NH
    float* agg    = h + NH;                    // NH
    float* aggT   = agg + NH;                  // NH
    float* siluT  = aggT + NH;                 // NH
    float* pk     = siluT + NH;                // 4*H*H = 1048576
    float* vbp    = pk + 4 * (H_DIM * H_DIM);  // 8*NH
    float* vb     = vbp + (size_t)ZSPLIT * NH; // NH
    float* vpart  = vb + NH;                   // 8*512
    float* vpart2 = vpart + 8 * H_DIM;         // 8*512
    float* xpart  = vpart2 + 8 * H_DIM;        // 16*1024
    float* xpart2 = xpart + 16 * F_DIM;        // 16*1024
    float* muv    = xpart2 + 16 * F_DIM;       // 512
    float* Sv     = muv + H_DIM;
    float* mux    = Sv + H_DIM;                // 1024
    float* Sx     = mux + F_DIM;
    float* pooled = Sx + F_DIM;                // 16*1536
    float* h1     = pooled + B_GRAPHS * FH_DIM;// 16*512
    int*   deg    = (int*)(h1 + B_GRAPHS * H_DIM); // 1024
    int*   estart = deg + N_NODES;
    int*   cursor = estart + N_NODES;
    int*   elist  = cursor + N_NODES;          // 32768
    int*   gstart = elist + E_EDGES;           // 16
    int*   gcnt   = gstart + 16;               // 16

    const int* src = eidx;
    const int* dst = eidx + E_EDGES;

    k_pre<<<3092, 256, 0, stream>>>(x, w_att, wk_scale, wk_trans, wk_wav, wk_base,
                                    h, pk, xpart, xpart2, deg);
    k_hist<<<E_EDGES / 256, 256, 0, stream>>>(dst, deg);
    k_scan2<<<2, 1024, 0, stream>>>(deg, estart, cursor, batch, gstart, gcnt);
    k_fill<<<E_EDGES / 256, 256, 0, stream>>>(src, dst, cursor, elist);
    k_gather<<<N_NODES, 256, 0, stream>>>(h, estart, deg, elist, agg);
    {
        dim3 grid(N_NODES / 64, H_DIM / 64);
        k_transpose<<<grid, 256, 0, stream>>>(agg, aggT, siluT);
    }
    {
        dim3 grid(N_NODES / TN, H_DIM / TO, ZSPLIT);
        k_wavelet<<<grid, 256, 0, stream>>>(aggT, siluT, pk, vbp);
    }
    k_reduce<<<64, 256, 0, stream>>>(vbp, vb, vpart, vpart2);
    k_finalize<<<1, 256, 0, stream>>>(vpart, vpart2, xpart, xpart2, muv, Sv, mux, Sx);
    {
        dim3 grid(6, B_GRAPHS);
        k_pool<<<grid, 256, 0, stream>>>(x, vb, gstart, gcnt, mux, Sx, muv, Sv, pooled);
    }
    k_fc1<<<H_DIM / 4, 256, 0, stream>>>(pooled, fc1_w, fc1_b, h1);
    k_fc2<<<(B_GRAPHS * OUT_DIM * 64 + 255) / 256, 256, 0, stream>>>(h1, fc2_w, fc2_b, outp);
}